// Round 4
// baseline (231.729 us; speedup 1.0000x reference)
//
#include <hip/hip_runtime.h>
#include <stdint.h>

// GPTQ 4-bit fused dequant-GEMM, MI355X gfx950.  Round 10.
// M=128, K=4096, N=11008, group=128, g_idx[k]=k>>7 (affine).
//
// R9 (128m x 16n x 64k wave retile) = 101.0 us; top-5 all harness 256MiB
// ws-fills (~87us fixed) -> controllable ~14us (prep 1.5, gemm ~7, reduce
// ~2.8, gaps ~2).  R10 deletes the k_reduce DISPATCH (not its traffic):
//  * last-block split-K merge: all 4 column blocks store f16 partials,
//    __threadfence (release), one atomicAdd on cnt[nb] per block (688
//    device-scope RMWs total -- R8's lesson: once per BLOCK is cheap, per
//    element is not).  The old==3 block acquire-fences (invalidates stale
//    poisoned L2 lines) and merges 3 partials + bias + its own f32 regs
//    straight into out.  No spin -> no deadlock; merge overlaps the gemm
//    tail instead of serializing behind a kernel boundary.
//  * cnt[172] zeroed by one extra k_prep block (kernel-boundary ordering).
//  * one of four splits now merges from f32 regs, not f16 -> precision up.
// Unchanged: exact-cancellation f16 magic dequant, XOR-swizzled async
// global_load_lds A-dbuf, 8 waves = 4 n-slices x 2 k-halves, LDS pair
// reduction, split-K x4 grid (172,4), packed {s,-z1} szp table.

#define M_DIM 128
#define K_DIM 4096
#define N_DIM 11008
#define GS    128
#define NG    32
#define SPLIT 4
#define GPB   (NG / SPLIT)           // 8 groups per block
#define NB    (N_DIM / 64)           // 172 n-blocks
#define PART_ELEMS ((size_t)NB * 4 * 2048)   // halfs per split = 1,409,024

typedef _Float16 half8  __attribute__((ext_vector_type(8)));
typedef _Float16 half2t __attribute__((ext_vector_type(2)));
typedef _Float16 half4t __attribute__((ext_vector_type(4)));
typedef float    f32x4  __attribute__((ext_vector_type(4)));

// ---------------- prep ------------------------------------------------------
// blocks [0,512):     x f32 -> xh f16                 (512*256*4 == 524288)
// blocks [512,1888):  szp packed {s, -(z+1)s} f16x2   (32 g x 43 nb x 256)
// block  1888:        cnt[0..171] = 0
__global__ void k_prep(const float* __restrict__ x, const int* __restrict__ qzeros,
                       const float* __restrict__ scales,
                       _Float16* __restrict__ xh, _Float16* __restrict__ szp,
                       int* __restrict__ cnt) {
    int b = blockIdx.x, tid = threadIdx.x;
    if (b < 512) {
        int i = (b * 256 + tid) * 4;
        float4 v = *(const float4*)(x + i);
        half4t o;
        o[0] = (_Float16)v.x; o[1] = (_Float16)v.y;
        o[2] = (_Float16)v.z; o[3] = (_Float16)v.w;
        *(half4t*)(xh + i) = o;
    } else if (b < 1888) {
        b -= 512;
        int g = b / 43;
        int n = (b - g * 43) * 256 + tid;            // 43*256 == 11008 exact
        unsigned qz = (unsigned)qzeros[g * (N_DIM / 8) + (n >> 3)];
        float s  = scales[g * N_DIM + n];
        float z1 = (float)((qz >> ((n & 7) * 4)) & 15u) + 1.0f;
        half2t o;
        o[0] = (_Float16)s;
        o[1] = (_Float16)(-(z1 * s));
        *(half2t*)(szp + (size_t)(g * N_DIM + n) * 2) = o;
    } else {
        if (tid < NB) cnt[tid] = 0;
    }
}

// async 16B/lane global->LDS; lds base wave-uniform, lane i -> base + i*16.
__device__ __forceinline__ void load_lds16(const void* g, void* l) {
    __builtin_amdgcn_global_load_lds(
        (const __attribute__((address_space(1))) unsigned int*)g,
        (__attribute__((address_space(3))) unsigned int*)l, 16, 0, 0);
}

// nibble pair p (nibbles 2p, 2p+1) of q -> two f16 weights:
//  t  = {0x6400|nib_lo, 0x6400|nib_hi<<4} = {1024+q_lo, 1024+16*q_hi}
//  qf = t - 1024                  (EXACT in f16: integers <= 2048)
//  w  = fma(qf, {s, s/16}, {-z1}) where z1 = (z+1)*s
// No pointer casts: pure vector ops, SROA-safe (scratch regression guard).
__device__ __forceinline__ half8 dequant8(unsigned q, half2t S2, half2t Z2) {
    const half2t BIAS = __builtin_bit_cast(half2t, 0x64006400u);
    half2t w[4];
#pragma unroll
    for (int p = 0; p < 4; ++p) {
        unsigned r = __builtin_amdgcn_perm(q, q, 0x00010001u * (unsigned)p); // byte p -> bytes 0,2
        unsigned t = (r & 0x00F0000Fu) | 0x64006400u;                        // v_and_or_b32
        w[p] = __builtin_elementwise_fma(__builtin_bit_cast(half2t, t) - BIAS, S2, Z2);
    }
    half4t lo = __builtin_shufflevector(w[0], w[1], 0, 1, 2, 3);
    half4t hi = __builtin_shufflevector(w[2], w[3], 0, 1, 2, 3);
    return __builtin_shufflevector(lo, hi, 0, 1, 2, 3, 4, 5, 6, 7);
}

// ---------------- main fused kernel (with last-block split-K merge) --------
__global__ __launch_bounds__(512, 4)
void k_gemm(const _Float16* __restrict__ xh,     // [128][4096] f16
            const int*      __restrict__ qweight,// [512][11008] int32
            const _Float16* __restrict__ szp,    // [32][11008] packed {s,-z1}
            _Float16*       __restrict__ part,   // [SPLIT][flat] f16 partials
            const float*    __restrict__ bias,   // [11008]
            float*          __restrict__ out,    // [128][11008]
            int*            __restrict__ cnt)    // [NB] arrival counters
{
    // Double-buffered A tile: logical (m,kb) of buffer b at
    //   As[b][m*128 + (kb ^ (m&15))*8]   (halfs)
    // Staged so chunk c = it*512+tid lands at byte offset c*16.
    __shared__ _Float16 As[2][128 * 128];   // 2 x 32 KB
    __shared__ int lastflag;

    const int tid  = threadIdx.x;
    const int lane = tid & 63;
    const int w    = tid >> 6;    // 0..7
    const int ns   = w & 3;        // n-slice: cols ns*16 .. ns*16+15
    const int kh   = w >> 2;       // k-half: kh=0 -> kk{0,1}, kh=1 -> kk{2,3}
    const int q    = lane >> 4;    // quad
    const int lr   = lane & 15;

    const int n0 = blockIdx.x * 64;
    const int g0 = blockIdx.y * GPB;
    const int ncol = n0 + ns * 16 + lr;

    f32x4 acc[8];
#pragma unroll
    for (int f = 0; f < 8; ++f)
        acc[f] = (f32x4){0.f, 0.f, 0.f, 0.f};

    // per-lane staging geometry: c = it*512 + tid; m=c>>4; kb=(c&15)^(m&15)
    int cm[4], ckb[4];
#pragma unroll
    for (int it = 0; it < 4; ++it) {
        int c = it * 512 + tid;
        cm[it]  = c >> 4;
        ckb[it] = (c & 15) ^ (cm[it] & 15);
    }
    const int wave_lds = w * 64 * 8;   // halfs

    // ---- prime group g0 ----
#pragma unroll
    for (int it = 0; it < 4; ++it)
        load_lds16(xh + (size_t)cm[it] * K_DIM + g0 * GS + ckb[it] * 8,
                   &As[0][it * 512 * 8 + wave_lds]);
    unsigned qwn[2];
    half2t   szn;
#pragma unroll
    for (int t = 0; t < 2; ++t)
        qwn[t] = (unsigned)qweight[(size_t)(g0 * 16 + (kh * 2 + t) * 4 + q) * N_DIM + ncol];
    szn = *(const half2t*)(szp + ((size_t)g0 * N_DIM + ncol) * 2);

    int p = 0;
    for (int g = 0; g < GPB; ++g) {
        unsigned qw[2];
        half2t   sz;
#pragma unroll
        for (int i = 0; i < 2; ++i) qw[i] = qwn[i];
        sz = szn;

        __syncthreads();   // A(g) resident in As[p]

        if (g + 1 < GPB) { // next group's async loads in flight under compute
            int gn = g0 + g + 1;
#pragma unroll
            for (int it = 0; it < 4; ++it)
                load_lds16(xh + (size_t)cm[it] * K_DIM + gn * GS + ckb[it] * 8,
                           &As[p ^ 1][it * 512 * 8 + wave_lds]);
#pragma unroll
            for (int t = 0; t < 2; ++t)
                qwn[t] = (unsigned)qweight[(size_t)(gn * 16 + (kh * 2 + t) * 4 + q) * N_DIM + ncol];
            szn = *(const half2t*)(szp + ((size_t)gn * N_DIM + ncol) * 2);
        }

        half2t S2, Z2;
        S2[0] = sz[0];
        S2[1] = sz[0] * (_Float16)0.0625f;   // exact pow2 scale
        Z2[0] = sz[1];
        Z2[1] = sz[1];

#pragma unroll
        for (int t = 0; t < 2; ++t) {
            const int kk = kh * 2 + t;
            half8 bf = dequant8(qw[t], S2, Z2);
            const int kb2 = (kk * 4 + q) ^ lr;   // m&15 == lr for all f below
#pragma unroll
            for (int f = 0; f < 8; ++f) {
                int m = f * 16 + lr;
                half8 af = *(const half8*)(&As[p][m * 128 + kb2 * 8]);
                acc[f] = __builtin_amdgcn_mfma_f32_16x16x32_f16(af, bf, acc[f], 0, 0, 0);
            }
        }
        p ^= 1;
    }

    // ---- pair reduction (w, w^4) through LDS ----
    __syncthreads();                       // all A reads done; LDS reusable
    float* red = (float*)&As[0][0];        // 32 KB: 4 pairs x 8 KB
    if (kh == 1) {
#pragma unroll
        for (int f = 0; f < 8; ++f)
            *(f32x4*)(red + ns * 2048 + f * 256 + lane * 4) = acc[f];
    }
    __syncthreads();

    // ---- store f16 partial (release) ----
    if (kh == 0) {
#pragma unroll
        for (int f = 0; f < 8; ++f)
            acc[f] += *(const f32x4*)(red + ns * 2048 + f * 256 + lane * 4);
        // flat layout: part[s][nb][ns][f][lane] as half4 -> 8B coalesced
        _Float16* ph = part + (size_t)blockIdx.y * PART_ELEMS
                     + (size_t)(blockIdx.x * 4 + ns) * 2048;
#pragma unroll
        for (int f = 0; f < 8; ++f) {
            half4t ov;
#pragma unroll
            for (int r = 0; r < 4; ++r) ov[r] = (_Float16)acc[f][r];
            *(half4t*)(ph + (f * 64 + lane) * 4) = ov;
        }
    }
    __threadfence();                       // release: partials device-visible
    __syncthreads();                       // all threads' fences done
    if (tid == 0)
        lastflag = (atomicAdd(&cnt[blockIdx.x], 1) == SPLIT - 1) ? 1 : 0;
    __syncthreads();

    // ---- last arriving block merges 3 partials + bias + own f32 regs ----
    if (lastflag && kh == 0) {
        __threadfence();                   // acquire: invalidate stale lines
        float bv = bias[ncol];
        const int my = blockIdx.y;
#pragma unroll
        for (int f = 0; f < 8; ++f) {
            f32x4 o = acc[f];
#pragma unroll
            for (int sp = 0; sp < SPLIT; ++sp) {
                if (sp == my) continue;
                half4t v = *(const half4t*)(part + (size_t)sp * PART_ELEMS
                          + (size_t)(blockIdx.x * 4 + ns) * 2048 + (f * 64 + lane) * 4);
#pragma unroll
                for (int r = 0; r < 4; ++r) o[r] += (float)v[r];
            }
#pragma unroll
            for (int r = 0; r < 4; ++r)
                out[(size_t)(f * 16 + q * 4 + r) * N_DIM + ncol] = o[r] + bv;
        }
    }
}

extern "C" void kernel_launch(void* const* d_in, const int* in_sizes, int n_in,
                              void* d_out, int out_size, void* d_ws, size_t ws_size,
                              hipStream_t stream) {
    const float* x       = (const float*)d_in[0];
    const int*   qweight = (const int*)d_in[1];
    const int*   qzeros  = (const int*)d_in[2];
    const float* scales  = (const float*)d_in[3];
    const float* bias    = (const float*)d_in[4];
    // d_in[5] = g_idx, affine by construction -> unused

    char* ws = (char*)d_ws;
    _Float16* xh   = (_Float16*)ws;                          // 1,048,576 B
    _Float16* szp  = (_Float16*)(ws + 1048576);              // 1,409,024 B
    _Float16* part = (_Float16*)(ws + 2457600);              // 4 x 2,818,048 B
    int*      cnt  = (int*)(ws + 2457600 + 4 * 2818048);     // 688 B

    k_prep<<<dim3(1889),        dim3(256), 0, stream>>>(x, qzeros, scales, xh, szp, cnt);
    k_gemm<<<dim3(NB, SPLIT),   dim3(512), 0, stream>>>(xh, qweight, szp, part,
                                                        bias, (float*)d_out, cnt);
}

// Round 5
// 103.050 us; speedup vs baseline: 2.2487x; 2.2487x over previous
//
#include <hip/hip_runtime.h>
#include <stdint.h>

// GPTQ 4-bit fused dequant-GEMM, MI355X gfx950.  Round 11.
// M=128, K=4096, N=11008, group=128, g_idx[k]=k>>7 (affine).
//
// R10 (last-block merge w/ per-block __threadfence) = 231.7 us DISASTER:
// k_gemm 164us with MfmaUtil 2.7% / VALU 4.2% / HBM 227 GB/s -- device-scope
// release fences (688x L2 writeback) serialized the kernel.  Lesson: on
// gfx950 the only cheap split-K fence is the kernel boundary.
// R11 goes the other way: DELETE split-K.  R9's verified wave layout
// (4 n-slices x 2 k-halves) with SPLIT=1, GPB=32, grid (172):
//  * qweight still read exactly once (22.5 MB); partials gone (-22.6 MB
//    round-trip), k_reduce + its launch gap gone; out written once, f32,
//    bias fused in epilogue.  Kernel HBM ~50.7 -> ~29 MB.
//  * precision up: pure f32 accumulate + LDS pair-merge, no f16 partials.
//  * cost: 172 blocks -> 1 block/CU, 2 waves/SIMD; serial K-loop 32 groups.
//    Required qweight BW ~5 TB/s < 6.3 achievable; prefetch depth 1 group.
// Unchanged: exact-cancellation f16 magic dequant, XOR-swizzled async
// global_load_lds A-dbuf, packed {s,-z1} szp table, LDS pair reduction.

#define M_DIM 128
#define K_DIM 4096
#define N_DIM 11008
#define GS    128
#define NG    32
#define GPB   NG                     // 32 groups per block (full K)
#define NB    (N_DIM / 64)           // 172 n-blocks

typedef _Float16 half8  __attribute__((ext_vector_type(8)));
typedef _Float16 half2t __attribute__((ext_vector_type(2)));
typedef _Float16 half4t __attribute__((ext_vector_type(4)));
typedef float    f32x4  __attribute__((ext_vector_type(4)));

// ---------------- prep ------------------------------------------------------
// blocks [0,512):     x f32 -> xh f16                 (512*256*4 == 524288)
// blocks [512,1888):  szp packed {s, -(z+1)s} f16x2   (32 g x 43 nb x 256)
__global__ void k_prep(const float* __restrict__ x, const int* __restrict__ qzeros,
                       const float* __restrict__ scales,
                       _Float16* __restrict__ xh, _Float16* __restrict__ szp) {
    int b = blockIdx.x, tid = threadIdx.x;
    if (b < 512) {
        int i = (b * 256 + tid) * 4;
        float4 v = *(const float4*)(x + i);
        half4t o;
        o[0] = (_Float16)v.x; o[1] = (_Float16)v.y;
        o[2] = (_Float16)v.z; o[3] = (_Float16)v.w;
        *(half4t*)(xh + i) = o;
    } else {
        b -= 512;
        int g = b / 43;
        int n = (b - g * 43) * 256 + tid;            // 43*256 == 11008 exact
        unsigned qz = (unsigned)qzeros[g * (N_DIM / 8) + (n >> 3)];
        float s  = scales[g * N_DIM + n];
        float z1 = (float)((qz >> ((n & 7) * 4)) & 15u) + 1.0f;
        half2t o;
        o[0] = (_Float16)s;
        o[1] = (_Float16)(-(z1 * s));
        *(half2t*)(szp + (size_t)(g * N_DIM + n) * 2) = o;
    }
}

// async 16B/lane global->LDS; lds base wave-uniform, lane i -> base + i*16.
__device__ __forceinline__ void load_lds16(const void* g, void* l) {
    __builtin_amdgcn_global_load_lds(
        (const __attribute__((address_space(1))) unsigned int*)g,
        (__attribute__((address_space(3))) unsigned int*)l, 16, 0, 0);
}

// nibble pair p (nibbles 2p, 2p+1) of q -> two f16 weights:
//  t  = {0x6400|nib_lo, 0x6400|nib_hi<<4} = {1024+q_lo, 1024+16*q_hi}
//  qf = t - 1024                  (EXACT in f16: integers <= 2048)
//  w  = fma(qf, {s, s/16}, {-z1}) where z1 = (z+1)*s
// No pointer casts: pure vector ops, SROA-safe (scratch regression guard).
__device__ __forceinline__ half8 dequant8(unsigned q, half2t S2, half2t Z2) {
    const half2t BIAS = __builtin_bit_cast(half2t, 0x64006400u);
    half2t w[4];
#pragma unroll
    for (int p = 0; p < 4; ++p) {
        unsigned r = __builtin_amdgcn_perm(q, q, 0x00010001u * (unsigned)p); // byte p -> bytes 0,2
        unsigned t = (r & 0x00F0000Fu) | 0x64006400u;                        // v_and_or_b32
        w[p] = __builtin_elementwise_fma(__builtin_bit_cast(half2t, t) - BIAS, S2, Z2);
    }
    half4t lo = __builtin_shufflevector(w[0], w[1], 0, 1, 2, 3);
    half4t hi = __builtin_shufflevector(w[2], w[3], 0, 1, 2, 3);
    return __builtin_shufflevector(lo, hi, 0, 1, 2, 3, 4, 5, 6, 7);
}

// ---------------- main fused kernel (full K, no split) ----------------
__global__ __launch_bounds__(512, 4)
void k_gemm(const _Float16* __restrict__ xh,     // [128][4096] f16
            const int*      __restrict__ qweight,// [512][11008] int32
            const _Float16* __restrict__ szp,    // [32][11008] packed {s,-z1}
            const float*    __restrict__ bias,   // [11008]
            float*          __restrict__ out)    // [128][11008]
{
    // Double-buffered A tile: logical (m,kb) of buffer b at
    //   As[b][m*128 + (kb ^ (m&15))*8]   (halfs)
    // Staged so chunk c = it*512+tid lands at byte offset c*16.
    __shared__ _Float16 As[2][128 * 128];   // 2 x 32 KB

    const int tid  = threadIdx.x;
    const int lane = tid & 63;
    const int w    = tid >> 6;    // 0..7
    const int ns   = w & 3;        // n-slice: cols ns*16 .. ns*16+15
    const int kh   = w >> 2;       // k-half: kh=0 -> kk{0,1}, kh=1 -> kk{2,3}
    const int q    = lane >> 4;    // quad
    const int lr   = lane & 15;

    const int n0 = blockIdx.x * 64;
    const int ncol = n0 + ns * 16 + lr;

    f32x4 acc[8];
#pragma unroll
    for (int f = 0; f < 8; ++f)
        acc[f] = (f32x4){0.f, 0.f, 0.f, 0.f};

    // per-lane staging geometry: c = it*512 + tid; m=c>>4; kb=(c&15)^(m&15)
    int cm[4], ckb[4];
#pragma unroll
    for (int it = 0; it < 4; ++it) {
        int c = it * 512 + tid;
        cm[it]  = c >> 4;
        ckb[it] = (c & 15) ^ (cm[it] & 15);
    }
    const int wave_lds = w * 64 * 8;   // halfs

    // ---- prime group 0 ----
#pragma unroll
    for (int it = 0; it < 4; ++it)
        load_lds16(xh + (size_t)cm[it] * K_DIM + ckb[it] * 8,
                   &As[0][it * 512 * 8 + wave_lds]);
    unsigned qwn[2];
    half2t   szn;
#pragma unroll
    for (int t = 0; t < 2; ++t)
        qwn[t] = (unsigned)qweight[(size_t)((kh * 2 + t) * 4 + q) * N_DIM + ncol];
    szn = *(const half2t*)(szp + (size_t)ncol * 2);

    int p = 0;
    for (int g = 0; g < GPB; ++g) {
        unsigned qw[2];
        half2t   sz;
#pragma unroll
        for (int i = 0; i < 2; ++i) qw[i] = qwn[i];
        sz = szn;

        __syncthreads();   // A(g) resident in As[p]

        if (g + 1 < GPB) { // next group's async loads in flight under compute
            int gn = g + 1;
#pragma unroll
            for (int it = 0; it < 4; ++it)
                load_lds16(xh + (size_t)cm[it] * K_DIM + gn * GS + ckb[it] * 8,
                           &As[p ^ 1][it * 512 * 8 + wave_lds]);
#pragma unroll
            for (int t = 0; t < 2; ++t)
                qwn[t] = (unsigned)qweight[(size_t)(gn * 16 + (kh * 2 + t) * 4 + q) * N_DIM + ncol];
            szn = *(const half2t*)(szp + ((size_t)gn * N_DIM + ncol) * 2);
        }

        half2t S2, Z2;
        S2[0] = sz[0];
        S2[1] = sz[0] * (_Float16)0.0625f;   // exact pow2 scale
        Z2[0] = sz[1];
        Z2[1] = sz[1];

#pragma unroll
        for (int t = 0; t < 2; ++t) {
            const int kk = kh * 2 + t;
            half8 bf = dequant8(qw[t], S2, Z2);
            const int kb2 = (kk * 4 + q) ^ lr;   // m&15 == lr for all f below
#pragma unroll
            for (int f = 0; f < 8; ++f) {
                int m = f * 16 + lr;
                half8 af = *(const half8*)(&As[p][m * 128 + kb2 * 8]);
                acc[f] = __builtin_amdgcn_mfma_f32_16x16x32_f16(af, bf, acc[f], 0, 0, 0);
            }
        }
        p ^= 1;
    }

    // ---- pair reduction (w, w^4) through LDS, then f32 out + bias ----
    __syncthreads();                       // all A reads done; LDS reusable
    float* red = (float*)&As[0][0];        // 32 KB: 4 pairs x 8 KB
    if (kh == 1) {
#pragma unroll
        for (int f = 0; f < 8; ++f)
            *(f32x4*)(red + ns * 2048 + f * 256 + lane * 4) = acc[f];
    }
    __syncthreads();
    if (kh == 0) {
        float bv = bias[ncol];
#pragma unroll
        for (int f = 0; f < 8; ++f) {
            f32x4 o = acc[f] + *(const f32x4*)(red + ns * 2048 + f * 256 + lane * 4);
#pragma unroll
            for (int r = 0; r < 4; ++r)
                out[(size_t)(f * 16 + q * 4 + r) * N_DIM + ncol] = o[r] + bv;
        }
    }
}

extern "C" void kernel_launch(void* const* d_in, const int* in_sizes, int n_in,
                              void* d_out, int out_size, void* d_ws, size_t ws_size,
                              hipStream_t stream) {
    const float* x       = (const float*)d_in[0];
    const int*   qweight = (const int*)d_in[1];
    const int*   qzeros  = (const int*)d_in[2];
    const float* scales  = (const float*)d_in[3];
    const float* bias    = (const float*)d_in[4];
    // d_in[5] = g_idx, affine by construction -> unused

    char* ws = (char*)d_ws;
    _Float16* xh  = (_Float16*)ws;                           // 1,048,576 B
    _Float16* szp = (_Float16*)(ws + 1048576);               // 1,409,024 B

    k_prep<<<dim3(1888), dim3(256), 0, stream>>>(x, qzeros, scales, xh, szp);
    k_gemm<<<dim3(NB),   dim3(512), 0, stream>>>(xh, qweight, szp, bias, (float*)d_out);
}

// Round 6
// 101.750 us; speedup vs baseline: 2.2774x; 1.0128x over previous
//
#include <hip/hip_runtime.h>
#include <stdint.h>

// GPTQ 4-bit fused dequant-GEMM, MI355X gfx950.  Round 12.
// M=128, K=4096, N=11008, group=128, g_idx[k]=k>>7 (affine).
//
// R11 (SPLIT=1) = 103.05: 172 blocks -> 2 waves/SIMD, 84 CUs idle; occupancy
// loss > merge savings.  Split-K design space now closed: f16 partials +
// kernel-boundary k_reduce (R9, 100.96) is optimal.
// R12 = R9 structure retiled for v_mfma_f32_32x32x16_f16 (2382 vs 2075 TF:
// floor 5.6 -> 4.84 us; MFMA instr 704K -> 176K; ds_read_b128/wave/group
// 16 -> 8; MFMA cyc/wave/group 77.6 -> 64.6):
//  * 8 waves = 2 n-slices(32) x 4 k-quarters(32k); wave = 128m x 32n x 32k.
//  * B-operand: lane l = col l&31, k=(l>>5)*8+j -- one qword per lane per
//    MFMA, dequant8 output feeds B directly (same 8-consecutive-k family as
//    the verified 16x16x32 mapping).
//  * A-tile LDS layout/staging/XOR swizzle/prefetch UNCHANGED; reads at
//    kb = kq*4+mf*2+hl, m = f*32+(lane&31).
//  * epilogue: 2-round LDS k-quarter reduction (64KB exact), kq==0 waves
//    store flat f16 partials; k_reduce decodes the 32x32 C layout
//    (row = f*32 + (reg&3) + 8*(reg>>2) + 4*hl, col = lane&31).
// Unchanged: exact-cancellation f16 magic dequant, packed {s,-z1} szp,
// split-K x4 grid (172,4), f16 flat partials + k_reduce fence.

#define M_DIM 128
#define K_DIM 4096
#define N_DIM 11008
#define GS    128
#define NG    32
#define SPLIT 4
#define GPB   (NG / SPLIT)           // 8 groups per block
#define NB    (N_DIM / 64)           // 172 n-blocks
#define PART_ELEMS ((size_t)NB * 2 * 4096)   // halfs per split = 1,409,024

typedef _Float16 half8  __attribute__((ext_vector_type(8)));
typedef _Float16 half2t __attribute__((ext_vector_type(2)));
typedef _Float16 half4t __attribute__((ext_vector_type(4)));
typedef float    f32x4  __attribute__((ext_vector_type(4)));
typedef float    f32x16 __attribute__((ext_vector_type(16)));

// ---------------- prep ------------------------------------------------------
// blocks [0,512):     x f32 -> xh f16                 (512*256*4 == 524288)
// blocks [512,1888):  szp packed {s, -(z+1)s} f16x2   (32 g x 43 nb x 256)
__global__ void k_prep(const float* __restrict__ x, const int* __restrict__ qzeros,
                       const float* __restrict__ scales,
                       _Float16* __restrict__ xh, _Float16* __restrict__ szp) {
    int b = blockIdx.x, tid = threadIdx.x;
    if (b < 512) {
        int i = (b * 256 + tid) * 4;
        float4 v = *(const float4*)(x + i);
        half4t o;
        o[0] = (_Float16)v.x; o[1] = (_Float16)v.y;
        o[2] = (_Float16)v.z; o[3] = (_Float16)v.w;
        *(half4t*)(xh + i) = o;
    } else {
        b -= 512;
        int g = b / 43;
        int n = (b - g * 43) * 256 + tid;            // 43*256 == 11008 exact
        unsigned qz = (unsigned)qzeros[g * (N_DIM / 8) + (n >> 3)];
        float s  = scales[g * N_DIM + n];
        float z1 = (float)((qz >> ((n & 7) * 4)) & 15u) + 1.0f;
        half2t o;
        o[0] = (_Float16)s;
        o[1] = (_Float16)(-(z1 * s));
        *(half2t*)(szp + (size_t)(g * N_DIM + n) * 2) = o;
    }
}

// async 16B/lane global->LDS; lds base wave-uniform, lane i -> base + i*16.
__device__ __forceinline__ void load_lds16(const void* g, void* l) {
    __builtin_amdgcn_global_load_lds(
        (const __attribute__((address_space(1))) unsigned int*)g,
        (__attribute__((address_space(3))) unsigned int*)l, 16, 0, 0);
}

// nibble pair p (nibbles 2p, 2p+1) of q -> two f16 weights:
//  t  = {0x6400|nib_lo, 0x6400|nib_hi<<4} = {1024+q_lo, 1024+16*q_hi}
//  qf = t - 1024                  (EXACT in f16: integers <= 2048)
//  w  = fma(qf, {s, s/16}, {-z1}) where z1 = (z+1)*s
// No pointer casts: pure vector ops, SROA-safe (scratch regression guard).
__device__ __forceinline__ half8 dequant8(unsigned q, half2t S2, half2t Z2) {
    const half2t BIAS = __builtin_bit_cast(half2t, 0x64006400u);
    half2t w[4];
#pragma unroll
    for (int p = 0; p < 4; ++p) {
        unsigned r = __builtin_amdgcn_perm(q, q, 0x00010001u * (unsigned)p); // byte p -> bytes 0,2
        unsigned t = (r & 0x00F0000Fu) | 0x64006400u;                        // v_and_or_b32
        w[p] = __builtin_elementwise_fma(__builtin_bit_cast(half2t, t) - BIAS, S2, Z2);
    }
    half4t lo = __builtin_shufflevector(w[0], w[1], 0, 1, 2, 3);
    half4t hi = __builtin_shufflevector(w[2], w[3], 0, 1, 2, 3);
    return __builtin_shufflevector(lo, hi, 0, 1, 2, 3, 4, 5, 6, 7);
}

// ---------------- main fused kernel ----------------
__global__ __launch_bounds__(512, 4)
void k_gemm(const _Float16* __restrict__ xh,     // [128][4096] f16
            const int*      __restrict__ qweight,// [512][11008] int32
            const _Float16* __restrict__ szp,    // [32][11008] packed {s,-z1}
            _Float16*       __restrict__ part)   // [SPLIT][flat] f16 partials
{
    // Double-buffered A tile: logical (m,kb) of buffer b at
    //   As[b][m*128 + (kb ^ (m&15))*8]   (halfs)
    // Staged so chunk c = it*512+tid lands at byte offset c*16.
    __shared__ _Float16 As[2][128 * 128];   // 2 x 32 KB

    const int tid  = threadIdx.x;
    const int lane = tid & 63;
    const int w    = tid >> 6;    // 0..7
    const int nsl  = w & 1;        // n-slice: cols nsl*32 .. +31
    const int kq   = w >> 1;       // k-quarter: k in [kq*32, kq*32+32) per group
    const int hl   = lane >> 5;    // half-wave
    const int l31  = lane & 31;

    const int n0 = blockIdx.x * 64;
    const int g0 = blockIdx.y * GPB;
    const int ncol = n0 + nsl * 32 + l31;

    f32x16 acc[4];
#pragma unroll
    for (int f = 0; f < 4; ++f)
#pragma unroll
        for (int e = 0; e < 16; ++e)
            acc[f][e] = 0.f;

    // per-lane staging geometry: c = it*512 + tid; m=c>>4; kb=(c&15)^(m&15)
    int cm[4], ckb[4];
#pragma unroll
    for (int it = 0; it < 4; ++it) {
        int c = it * 512 + tid;
        cm[it]  = c >> 4;
        ckb[it] = (c & 15) ^ (cm[it] & 15);
    }
    const int wave_lds = w * 64 * 8;   // halfs

    // ---- prime group g0 ----
#pragma unroll
    for (int it = 0; it < 4; ++it)
        load_lds16(xh + (size_t)cm[it] * K_DIM + g0 * GS + ckb[it] * 8,
                   &As[0][it * 512 * 8 + wave_lds]);
    unsigned qwn[2];
    half2t   szn;
#pragma unroll
    for (int mf = 0; mf < 2; ++mf)
        qwn[mf] = (unsigned)qweight[(size_t)(g0 * 16 + kq * 4 + mf * 2 + hl) * N_DIM + ncol];
    szn = *(const half2t*)(szp + ((size_t)g0 * N_DIM + ncol) * 2);

    int p = 0;
    for (int g = 0; g < GPB; ++g) {
        unsigned qw[2];
        half2t   sz;
#pragma unroll
        for (int i = 0; i < 2; ++i) qw[i] = qwn[i];
        sz = szn;

        __syncthreads();   // A(g) resident in As[p]

        if (g + 1 < GPB) { // next group's async loads in flight under compute
            int gn = g0 + g + 1;
#pragma unroll
            for (int it = 0; it < 4; ++it)
                load_lds16(xh + (size_t)cm[it] * K_DIM + gn * GS + ckb[it] * 8,
                           &As[p ^ 1][it * 512 * 8 + wave_lds]);
#pragma unroll
            for (int mf = 0; mf < 2; ++mf)
                qwn[mf] = (unsigned)qweight[(size_t)(gn * 16 + kq * 4 + mf * 2 + hl) * N_DIM + ncol];
            szn = *(const half2t*)(szp + ((size_t)gn * N_DIM + ncol) * 2);
        }

        half2t S2, Z2;
        S2[0] = sz[0];
        S2[1] = sz[0] * (_Float16)0.0625f;   // exact pow2 scale
        Z2[0] = sz[1];
        Z2[1] = sz[1];

#pragma unroll
        for (int mf = 0; mf < 2; ++mf) {
            half8 bf = dequant8(qw[mf], S2, Z2);
            const int kb_sw = (kq * 4 + mf * 2 + hl) ^ (lane & 15);
#pragma unroll
            for (int f = 0; f < 4; ++f) {
                int m = f * 32 + l31;
                half8 af = *(const half8*)(&As[p][m * 128 + kb_sw * 8]);
                acc[f] = __builtin_amdgcn_mfma_f32_32x32x16_f16(af, bf, acc[f], 0, 0, 0);
            }
        }
        p ^= 1;
    }

    // ---- 2-round k-quarter reduction through LDS (64 KB = 4 x 16 KB slots) --
    __syncthreads();                       // all A reads done; LDS reusable
    float* red = (float*)&As[0][0];
    if (kq >= 2) {                         // round 1 writers: slots 0..3
        float* rw = red + ((nsl << 1) | (kq - 2)) * 4096;
#pragma unroll
        for (int f = 0; f < 4; ++f)
#pragma unroll
            for (int rg = 0; rg < 4; ++rg) {
                f32x4 v = { acc[f][rg*4+0], acc[f][rg*4+1],
                            acc[f][rg*4+2], acc[f][rg*4+3] };
                *(f32x4*)(rw + (f * 4 + rg) * 256 + lane * 4) = v;
            }
    }
    __syncthreads();
    if (kq < 2) {                          // round 1 readers
        const float* rd = red + ((nsl << 1) | kq) * 4096;
#pragma unroll
        for (int f = 0; f < 4; ++f)
#pragma unroll
            for (int rg = 0; rg < 4; ++rg) {
                f32x4 v = *(const f32x4*)(rd + (f * 4 + rg) * 256 + lane * 4);
#pragma unroll
                for (int r = 0; r < 4; ++r) acc[f][rg*4+r] += v[r];
            }
    }
    __syncthreads();                       // round-1 reads done before reuse
    if (kq == 1) {                         // round 2 writers: slots 0..1
        float* rw = red + nsl * 4096;
#pragma unroll
        for (int f = 0; f < 4; ++f)
#pragma unroll
            for (int rg = 0; rg < 4; ++rg) {
                f32x4 v = { acc[f][rg*4+0], acc[f][rg*4+1],
                            acc[f][rg*4+2], acc[f][rg*4+3] };
                *(f32x4*)(rw + (f * 4 + rg) * 256 + lane * 4) = v;
            }
    }
    __syncthreads();
    if (kq == 0) {                         // final merge + f16 partial store
        const float* rd = red + nsl * 4096;
        // flat layout: part[s][nb][nsl][f*4+rg][lane] as half4 -> 8B coalesced
        _Float16* ph = part + (size_t)blockIdx.y * PART_ELEMS
                     + (size_t)(blockIdx.x * 2 + nsl) * 4096;
#pragma unroll
        for (int f = 0; f < 4; ++f)
#pragma unroll
            for (int rg = 0; rg < 4; ++rg) {
                f32x4 v = *(const f32x4*)(rd + (f * 4 + rg) * 256 + lane * 4);
                half4t ov;
#pragma unroll
                for (int r = 0; r < 4; ++r)
                    ov[r] = (_Float16)(acc[f][rg*4+r] + v[r]);
                *(half4t*)(ph + ((f * 4 + rg) * 64 + lane) * 4) = ov;
            }
    }
}

// ---------------- reduce: out = bias + sum_s part[s] (decode 32x32 C) ------
__global__ void k_reduce(const _Float16* __restrict__ part, const float* __restrict__ bias,
                         float* __restrict__ out) {
    int t = blockIdx.x * 256 + threadIdx.x;   // 1376*256 = 352,256 = PART_ELEMS/4
    int lane = t & 63, fr = (t >> 6) & 15, nslot = t >> 10;
    int f = fr >> 2, rg = fr & 3;
    int nb = nslot >> 1, nsl = nslot & 1;
    int row0 = f * 32 + rg * 8 + ((lane >> 5) << 2);   // + rr for rr=0..3
    int col  = nb * 64 + nsl * 32 + (lane & 31);
    f32x4 sv = (f32x4){0.f, 0.f, 0.f, 0.f};
#pragma unroll
    for (int s = 0; s < SPLIT; ++s) {
        half4t v = *(const half4t*)(part + s * PART_ELEMS + (size_t)t * 4);
#pragma unroll
        for (int r = 0; r < 4; ++r) sv[r] += (float)v[r];
    }
    float b = bias[col];
#pragma unroll
    for (int r = 0; r < 4; ++r)
        out[(size_t)(row0 + r) * N_DIM + col] = sv[r] + b;
}

extern "C" void kernel_launch(void* const* d_in, const int* in_sizes, int n_in,
                              void* d_out, int out_size, void* d_ws, size_t ws_size,
                              hipStream_t stream) {
    const float* x       = (const float*)d_in[0];
    const int*   qweight = (const int*)d_in[1];
    const int*   qzeros  = (const int*)d_in[2];
    const float* scales  = (const float*)d_in[3];
    const float* bias    = (const float*)d_in[4];
    // d_in[5] = g_idx, affine by construction -> unused

    char* ws = (char*)d_ws;
    _Float16* xh   = (_Float16*)ws;                          // 1,048,576 B
    _Float16* szp  = (_Float16*)(ws + 1048576);              // 1,409,024 B
    _Float16* part = (_Float16*)(ws + 1048576 + 1409024);    // 4 x 2,818,048 B

    k_prep  <<<dim3(1888),         dim3(256), 0, stream>>>(x, qzeros, scales, xh, szp);
    k_gemm  <<<dim3(NB, SPLIT),    dim3(512), 0, stream>>>(xh, qweight, szp, part);
    k_reduce<<<dim3(1376),         dim3(256), 0, stream>>>(part, bias, (float*)d_out);
}

// Round 7
// 100.437 us; speedup vs baseline: 2.3072x; 1.0131x over previous
//
#include <hip/hip_runtime.h>
#include <stdint.h>

// GPTQ 4-bit fused dequant-GEMM, MI355X gfx950.  Round 13.
// M=128, K=4096, N=11008, group=128, g_idx[k]=k>>7 (affine).
//
// R12 (32x32x16 MFMA retile) = 101.75: correct but the 2-round LDS epilogue
// ate the rate gain; R9 (100.96) remains best.  MFMA-shape and split-K-merge
// spaces closed.
// R13 = R9 + UNEVEN split-K {11,11,5,5} (makespan fix, nothing else):
//  * slot model: 512thr + 64KB LDS -> 2 blocks/CU -> 512 co-resident slots.
//    R9's 688 equal 8-unit blocks: 512 run [0,8], 176 run [8,16] at 34%
//    occupancy -> 67% utilization (gemm ~7us vs 5.6 floor).
//  * uneven boundaries {0,11,22,27,32}: 344 big(11u) blocks dispatch first
//    (x-fastest order), 344 small(5u) fill slots as they free: makespan
//    16 -> ~11 units (98% of ideal 10.75).  Only the k-sum grouping changes.
//  * partial layout, k_reduce, inner loop, staging: byte-identical to R9.
// Unchanged: exact-cancellation f16 magic dequant, XOR-swizzled async
// global_load_lds A-dbuf, 8 waves = 4 n-slices x 2 k-halves, LDS pair
// reduction, packed {s,-z1} szp table, f16 flat partials + k_reduce fence.

#define M_DIM 128
#define K_DIM 4096
#define N_DIM 11008
#define GS    128
#define NG    32
#define SPLIT 4
#define NB    (N_DIM / 64)           // 172 n-blocks
#define PART_ELEMS ((size_t)NB * 4 * 2048)   // halfs per split = 1,409,024

typedef _Float16 half8  __attribute__((ext_vector_type(8)));
typedef _Float16 half2t __attribute__((ext_vector_type(2)));
typedef _Float16 half4t __attribute__((ext_vector_type(4)));
typedef float    f32x4  __attribute__((ext_vector_type(4)));

// uneven split boundaries: big splits first in dispatch order
__constant__ int g_bound[SPLIT + 1] = {0, 11, 22, 27, 32};

// ---------------- prep ------------------------------------------------------
// blocks [0,512):     x f32 -> xh f16                 (512*256*4 == 524288)
// blocks [512,1888):  szp packed {s, -(z+1)s} f16x2   (32 g x 43 nb x 256)
__global__ void k_prep(const float* __restrict__ x, const int* __restrict__ qzeros,
                       const float* __restrict__ scales,
                       _Float16* __restrict__ xh, _Float16* __restrict__ szp) {
    int b = blockIdx.x, tid = threadIdx.x;
    if (b < 512) {
        int i = (b * 256 + tid) * 4;
        float4 v = *(const float4*)(x + i);
        half4t o;
        o[0] = (_Float16)v.x; o[1] = (_Float16)v.y;
        o[2] = (_Float16)v.z; o[3] = (_Float16)v.w;
        *(half4t*)(xh + i) = o;
    } else {
        b -= 512;
        int g = b / 43;
        int n = (b - g * 43) * 256 + tid;            // 43*256 == 11008 exact
        unsigned qz = (unsigned)qzeros[g * (N_DIM / 8) + (n >> 3)];
        float s  = scales[g * N_DIM + n];
        float z1 = (float)((qz >> ((n & 7) * 4)) & 15u) + 1.0f;
        half2t o;
        o[0] = (_Float16)s;
        o[1] = (_Float16)(-(z1 * s));
        *(half2t*)(szp + (size_t)(g * N_DIM + n) * 2) = o;
    }
}

// async 16B/lane global->LDS; lds base wave-uniform, lane i -> base + i*16.
__device__ __forceinline__ void load_lds16(const void* g, void* l) {
    __builtin_amdgcn_global_load_lds(
        (const __attribute__((address_space(1))) unsigned int*)g,
        (__attribute__((address_space(3))) unsigned int*)l, 16, 0, 0);
}

// nibble pair p (nibbles 2p, 2p+1) of q -> two f16 weights:
//  t  = {0x6400|nib_lo, 0x6400|nib_hi<<4} = {1024+q_lo, 1024+16*q_hi}
//  qf = t - 1024                  (EXACT in f16: integers <= 2048)
//  w  = fma(qf, {s, s/16}, {-z1}) where z1 = (z+1)*s
// No pointer casts: pure vector ops, SROA-safe (scratch regression guard).
__device__ __forceinline__ half8 dequant8(unsigned q, half2t S2, half2t Z2) {
    const half2t BIAS = __builtin_bit_cast(half2t, 0x64006400u);
    half2t w[4];
#pragma unroll
    for (int p = 0; p < 4; ++p) {
        unsigned r = __builtin_amdgcn_perm(q, q, 0x00010001u * (unsigned)p); // byte p -> bytes 0,2
        unsigned t = (r & 0x00F0000Fu) | 0x64006400u;                        // v_and_or_b32
        w[p] = __builtin_elementwise_fma(__builtin_bit_cast(half2t, t) - BIAS, S2, Z2);
    }
    half4t lo = __builtin_shufflevector(w[0], w[1], 0, 1, 2, 3);
    half4t hi = __builtin_shufflevector(w[2], w[3], 0, 1, 2, 3);
    return __builtin_shufflevector(lo, hi, 0, 1, 2, 3, 4, 5, 6, 7);
}

// ---------------- main fused kernel ----------------
__global__ __launch_bounds__(512, 4)
void k_gemm(const _Float16* __restrict__ xh,     // [128][4096] f16
            const int*      __restrict__ qweight,// [512][11008] int32
            const _Float16* __restrict__ szp,    // [32][11008] packed {s,-z1}
            _Float16*       __restrict__ part)   // [SPLIT][flat] f16 partials
{
    // Double-buffered A tile: logical (m,kb) of buffer b at
    //   As[b][m*128 + (kb ^ (m&15))*8]   (halfs)
    // Staged so chunk c = it*512+tid lands at byte offset c*16.
    __shared__ _Float16 As[2][128 * 128];   // 2 x 32 KB

    const int tid  = threadIdx.x;
    const int lane = tid & 63;
    const int w    = tid >> 6;    // 0..7
    const int ns   = w & 3;        // n-slice: cols ns*16 .. ns*16+15
    const int kh   = w >> 2;       // k-half: kh=0 -> kk{0,1}, kh=1 -> kk{2,3}
    const int q    = lane >> 4;    // quad
    const int lr   = lane & 15;

    const int n0 = blockIdx.x * 64;
    const int g0 = g_bound[blockIdx.y];
    const int g1 = g_bound[blockIdx.y + 1];
    const int ncol = n0 + ns * 16 + lr;

    f32x4 acc[8];
#pragma unroll
    for (int f = 0; f < 8; ++f)
        acc[f] = (f32x4){0.f, 0.f, 0.f, 0.f};

    // per-lane staging geometry: c = it*512 + tid; m=c>>4; kb=(c&15)^(m&15)
    int cm[4], ckb[4];
#pragma unroll
    for (int it = 0; it < 4; ++it) {
        int c = it * 512 + tid;
        cm[it]  = c >> 4;
        ckb[it] = (c & 15) ^ (cm[it] & 15);
    }
    const int wave_lds = w * 64 * 8;   // halfs

    // ---- prime group g0 ----
#pragma unroll
    for (int it = 0; it < 4; ++it)
        load_lds16(xh + (size_t)cm[it] * K_DIM + g0 * GS + ckb[it] * 8,
                   &As[0][it * 512 * 8 + wave_lds]);
    unsigned qwn[2];
    half2t   szn;
#pragma unroll
    for (int t = 0; t < 2; ++t)
        qwn[t] = (unsigned)qweight[(size_t)(g0 * 16 + (kh * 2 + t) * 4 + q) * N_DIM + ncol];
    szn = *(const half2t*)(szp + ((size_t)g0 * N_DIM + ncol) * 2);

    int p = 0;
    for (int g = g0; g < g1; ++g) {
        unsigned qw[2];
        half2t   sz;
#pragma unroll
        for (int i = 0; i < 2; ++i) qw[i] = qwn[i];
        sz = szn;

        __syncthreads();   // A(g) resident in As[p]

        if (g + 1 < g1) {  // next group's async loads in flight under compute
            int gn = g + 1;
#pragma unroll
            for (int it = 0; it < 4; ++it)
                load_lds16(xh + (size_t)cm[it] * K_DIM + gn * GS + ckb[it] * 8,
                           &As[p ^ 1][it * 512 * 8 + wave_lds]);
#pragma unroll
            for (int t = 0; t < 2; ++t)
                qwn[t] = (unsigned)qweight[(size_t)(gn * 16 + (kh * 2 + t) * 4 + q) * N_DIM + ncol];
            szn = *(const half2t*)(szp + ((size_t)gn * N_DIM + ncol) * 2);
        }

        half2t S2, Z2;
        S2[0] = sz[0];
        S2[1] = sz[0] * (_Float16)0.0625f;   // exact pow2 scale
        Z2[0] = sz[1];
        Z2[1] = sz[1];

#pragma unroll
        for (int t = 0; t < 2; ++t) {
            const int kk = kh * 2 + t;
            half8 bf = dequant8(qw[t], S2, Z2);
            const int kb2 = (kk * 4 + q) ^ lr;   // m&15 == lr for all f below
#pragma unroll
            for (int f = 0; f < 8; ++f) {
                int m = f * 16 + lr;
                half8 af = *(const half8*)(&As[p][m * 128 + kb2 * 8]);
                acc[f] = __builtin_amdgcn_mfma_f32_16x16x32_f16(af, bf, acc[f], 0, 0, 0);
            }
        }
        p ^= 1;
    }

    // ---- pair reduction (w, w^4) through LDS, then store f16 partials ----
    __syncthreads();                       // all A reads done; LDS reusable
    float* red = (float*)&As[0][0];        // 32 KB: 4 pairs x 8 KB
    if (kh == 1) {
#pragma unroll
        for (int f = 0; f < 8; ++f)
            *(f32x4*)(red + ns * 2048 + f * 256 + lane * 4) = acc[f];
    }
    __syncthreads();
    if (kh == 0) {
        // flat layout: part[s][nb][ns][f][lane] as half4 -> 8B coalesced
        _Float16* ph = part + (size_t)blockIdx.y * PART_ELEMS
                     + (size_t)(blockIdx.x * 4 + ns) * 2048;
#pragma unroll
        for (int f = 0; f < 8; ++f) {
            f32x4 o = acc[f] + *(const f32x4*)(red + ns * 2048 + f * 256 + lane * 4);
            half4t ov;
#pragma unroll
            for (int r = 0; r < 4; ++r) ov[r] = (_Float16)o[r];
            *(half4t*)(ph + (f * 64 + lane) * 4) = ov;
        }
    }
}

// ---------------- reduce: out = bias + sum_s part[s] (decode flat layout) ---
__global__ void k_reduce(const _Float16* __restrict__ part, const float* __restrict__ bias,
                         float* __restrict__ out) {
    int t = blockIdx.x * 256 + threadIdx.x;   // 1376*256 = 352,256 = PART_ELEMS/4
    int lane = t & 63, f = (t >> 6) & 7, ns = (t >> 9) & 3, nb = t >> 11;
    int q = lane >> 4, lr = lane & 15;
    int m0 = f * 16 + q * 4;
    int n  = nb * 64 + ns * 16 + lr;
    f32x4 sv = (f32x4){0.f, 0.f, 0.f, 0.f};
#pragma unroll
    for (int s = 0; s < SPLIT; ++s) {
        half4t v = *(const half4t*)(part + s * PART_ELEMS + (size_t)t * 4);
#pragma unroll
        for (int r = 0; r < 4; ++r) sv[r] += (float)v[r];
    }
    float b = bias[n];
#pragma unroll
    for (int r = 0; r < 4; ++r)
        out[(size_t)(m0 + r) * N_DIM + n] = sv[r] + b;
}

extern "C" void kernel_launch(void* const* d_in, const int* in_sizes, int n_in,
                              void* d_out, int out_size, void* d_ws, size_t ws_size,
                              hipStream_t stream) {
    const float* x       = (const float*)d_in[0];
    const int*   qweight = (const int*)d_in[1];
    const int*   qzeros  = (const int*)d_in[2];
    const float* scales  = (const float*)d_in[3];
    const float* bias    = (const float*)d_in[4];
    // d_in[5] = g_idx, affine by construction -> unused

    char* ws = (char*)d_ws;
    _Float16* xh   = (_Float16*)ws;                          // 1,048,576 B
    _Float16* szp  = (_Float16*)(ws + 1048576);              // 1,409,024 B
    _Float16* part = (_Float16*)(ws + 1048576 + 1409024);    // 4 x 2,818,048 B

    k_prep  <<<dim3(1888),         dim3(256), 0, stream>>>(x, qzeros, scales, xh, szp);
    k_gemm  <<<dim3(NB, SPLIT),    dim3(512), 0, stream>>>(xh, qweight, szp, part);
    k_reduce<<<dim3(1376),         dim3(256), 0, stream>>>(part, bias, (float*)d_out);
}